// Round 11
// baseline (186.722 us; speedup 1.0000x reference)
//
#include <hip/hip_runtime.h>
#include <hip/hip_bf16.h>
#include <stdint.h>

// ---------------------------------------------------------------------------
// Net_71373766525077: SNN leaky layer.
//   cur = x @ W^T   (1024x4096 @ 4096x4096 fp32; mem tol 7.92 -> bf16 MFMA)
//   scan t: reset=(mem>1); mem=0.9*mem+cur[t]-reset; spk=(mem>1)
//   out = concat(spk_rec[T][N], mem_rec[T][N]) fp32
//
// R10 -> R11 (ledger: OV ~80 fixed + cvt 19 + gemm 56 + scan ~27):
//  * scan phase depth PH_T 128 -> 256: barriers 9 -> 5 per block, LDS rings
//    66 KB (2 blocks/CU), 2x staging work amortized per barrier drain.
//  * spk/mem stores nontemporal (streamed output, never re-read).
//  * gemm (128^2, S=2, bf16 partials) and cvt unchanged - at plateau.
// ---------------------------------------------------------------------------

typedef __attribute__((ext_vector_type(8))) short bf16x8;
typedef __attribute__((ext_vector_type(4))) float floatx4;

#define T_STEPS 1024
#define N_IN    4096
#define N_OUT   4096

#define BM 128   // gemm M tile
#define BN 128   // gemm N tile
#define BKK 64   // K-chunk per LDS stage (bf16 elements)

#define PH_T 256                  // timesteps per scan phase
#define NPH  (T_STEPS / PH_T)     // 4 phases
#define NGRP (PH_T / 4)           // 64 row-groups of 4 timesteps
#define NB_N 16                   // neurons per scan block
#define TP   258                  // LDS t-stride (floats); 2pn banks -> <=2-way

#define TN ((size_t)T_STEPS * N_OUT)

__device__ __forceinline__ unsigned short f2bf_rne(float f) {
    unsigned int u = __builtin_bit_cast(unsigned int, f);
    unsigned int r = 0x7FFFu + ((u >> 16) & 1u);
    return (unsigned short)((u + r) >> 16);
}

__device__ __forceinline__ float bf2f(unsigned short b) {
    unsigned int u = ((unsigned int)b) << 16;
    return __builtin_bit_cast(float, u);
}

// One kernel converts both inputs (x then W), float4/ushort4 vectorized.
__global__ __launch_bounds__(256) void cvt2_kernel(const float4* __restrict__ inX,
                                                   ushort4* __restrict__ outX, int n4x,
                                                   const float4* __restrict__ inW,
                                                   ushort4* __restrict__ outW, int n4w) {
    int i = blockIdx.x * blockDim.x + threadIdx.x;
    const float4* in;
    ushort4* out;
    int k;
    if (i < n4x) { in = inX; out = outX; k = i; }
    else         { in = inW; out = outW; k = i - n4x; if (k >= n4w) return; }
    float4 v = in[k];
    ushort4 o;
    o.x = f2bf_rne(v.x);
    o.y = f2bf_rne(v.y);
    o.z = f2bf_rne(v.z);
    o.w = f2bf_rne(v.w);
    out[k] = o;
}

__device__ __forceinline__ void gload16(const void* g, void* l) {
    __builtin_amdgcn_global_load_lds((const __attribute__((address_space(1))) void*)g,
                                     (__attribute__((address_space(3))) void*)l,
                                     16, 0, 0);
}

// Pb[z][T][N] = A[M][kz] * B[N][kz]^T, bf16 in, bf16 partials out.
// 128x128 tile, grid = 256*S blocks (z = bid>>8, mt = (bid>>5)&7, nt = bid&31).
// 4 waves in 2x2, each 64x64 via 4x4 of 16x16x32 MFMA.
__global__ __launch_bounds__(256) void gemm_bt(const short* __restrict__ A,
                                               const short* __restrict__ B,
                                               unsigned short* __restrict__ Pb,
                                               int kLen) {
    __shared__ short sA[BM * BKK];  // 16 KB
    __shared__ short sB[BN * BKK];  // 16 KB

    const int tid  = threadIdx.x;
    const int lane = tid & 63;
    const int wv   = tid >> 6;
    const int wm   = (wv & 1) * 64;
    const int wn   = (wv >> 1) * 64;

    const int bid    = blockIdx.x;
    const int z      = bid >> 8;
    const int n_tile = bid & 31;
    const int m_tile = (bid >> 5) & 7;
    const long bm = (long)m_tile * BM;
    const long bn = (long)n_tile * BN;
    const int kBeg = z * kLen;
    const int kEnd = kBeg + kLen;
    unsigned short* __restrict__ Pz = Pb + (size_t)z * TN;

    floatx4 acc[4][4] = {};

    const int srow = tid >> 3;       // 0..31
    const int scol = (tid & 7) * 8;  // bf16 offset within 64-wide row
    const short* gA[4];
    const short* gB[4];
    short* lA[4];
    short* lB[4];
#pragma unroll
    for (int p = 0; p < 4; ++p) {
        gA[p] = A + (bm + p * 32 + srow) * (long)N_IN + scol;
        gB[p] = B + (bn + p * 32 + srow) * (long)N_IN + scol;
        lA[p] = sA + p * 2048 + tid * 8;
        lB[p] = sB + p * 2048 + tid * 8;
    }

    const int fm  = lane & 15;
    const int fko = (lane >> 4) * 8;

    for (int k0 = kBeg; k0 < kEnd; k0 += BKK) {
#pragma unroll
        for (int p = 0; p < 4; ++p) gload16(gA[p] + k0, lA[p]);
#pragma unroll
        for (int p = 0; p < 4; ++p) gload16(gB[p] + k0, lB[p]);
        __syncthreads();

#pragma unroll
        for (int ks = 0; ks < 2; ++ks) {
            bf16x8 af[4], bfr[4];
#pragma unroll
            for (int i = 0; i < 4; ++i)
                af[i] = *(const bf16x8*)(sA + (wm + i * 16 + fm) * 64 + ks * 32 + fko);
#pragma unroll
            for (int j = 0; j < 4; ++j)
                bfr[j] = *(const bf16x8*)(sB + (wn + j * 16 + fm) * 64 + ks * 32 + fko);
#pragma unroll
            for (int i = 0; i < 4; ++i)
#pragma unroll
                for (int j = 0; j < 4; ++j)
                    acc[i][j] = __builtin_amdgcn_mfma_f32_16x16x32_bf16(
                        af[i], bfr[j], acc[i][j], 0, 0, 0);
        }
        __syncthreads();
    }

    // C/D layout: col(n)=lane&15, row(m)=(lane>>4)*4+reg [m89/m91]
    const int cn = lane & 15;
    const int cm = (lane >> 4) * 4;
#pragma unroll
    for (int i = 0; i < 4; ++i)
#pragma unroll
        for (int j = 0; j < 4; ++j)
#pragma unroll
            for (int r = 0; r < 4; ++r)
                Pz[(bm + wm + i * 16 + cm + r) * (long)N_OUT + bn + wn + j * 16 + cn] =
                    f2bf_rne(acc[i][j][r]);
}

// Fused scan: 256 blocks x 512 threads; block owns NB_N=16 neurons for ALL t.
// Phases of PH_T=256 steps. Waves 0-6 (producers): write out phase ph-1
// spk/mem from ringMem (nontemporal), stage phase ph+1 of Pb (bf16, summing
// NPART partials) into ringCur. Wave 7 (consumer, lanes 0..15): serial
// recurrence ringCur -> ringMem. One barrier per phase (5 total incl prefill).
// Producer lane map: pn=lane&15 (n), tr=lane>>4 (t-row in group of 4);
// row-groups g = wv + 7*i, i<10, guard g<NGRP(=64).
template <int NPART>
__global__ __launch_bounds__(512) void scan_kernel(const unsigned short* __restrict__ Pb,
                                                   float* __restrict__ out) {
    __shared__ float ringCur[2][NB_N * TP];   // 33.0 KB
    __shared__ float ringMem[2][NB_N * TP];   // 33.0 KB

    const int tid  = threadIdx.x;
    const int wv   = tid >> 6;     // 0..7
    const int lane = tid & 63;
    const int n0   = blockIdx.x * NB_N;

    const int pn = lane & 15;   // neuron offset within block
    const int tr = lane >> 4;   // t-row 0..3 within a group of 4

    float mem = 0.0f;           // consumer state (wave 7, lanes 0..15)

    // ---- prefill: phase 0 -> ringCur[0] ----
    if (wv < 7) {
        float v[NPART][10];
        int gi[10];
#pragma unroll
        for (int i = 0; i < 10; ++i) {
            int g = wv + 7 * i;
            gi[i] = g;
            if (g < NGRP) {
                size_t idx = (size_t)(g * 4 + tr) * N_OUT + n0 + pn;
#pragma unroll
                for (int zz = 0; zz < NPART; ++zz)
                    v[zz][i] = bf2f(Pb[(size_t)zz * TN + idx]);
            }
        }
#pragma unroll
        for (int i = 0; i < 10; ++i)
            if (gi[i] < NGRP) {
                float s = v[0][i];
#pragma unroll
                for (int zz = 1; zz < NPART; ++zz) s += v[zz][i];
                ringCur[0][pn * TP + gi[i] * 4 + tr] = s;
            }
    }
    __syncthreads();

    for (int ph = 0; ph < NPH; ++ph) {
        if (wv < 7) {
            // (a) write out phase ph-1 results (nontemporal: streamed)
            if (ph >= 1) {
                const float* mr = ringMem[(ph - 1) & 1];
                const size_t tb = (size_t)(ph - 1) * PH_T;
                float mv[10];
                int gi[10];
#pragma unroll
                for (int i = 0; i < 10; ++i) {
                    int g = wv + 7 * i;
                    gi[i] = g;
                    if (g < NGRP) mv[i] = mr[pn * TP + g * 4 + tr];
                }
#pragma unroll
                for (int i = 0; i < 10; ++i)
                    if (gi[i] < NGRP) {
                        size_t idx = (tb + gi[i] * 4 + tr) * N_OUT + n0 + pn;
                        __builtin_nontemporal_store(mv[i] > 1.0f ? 1.0f : 0.0f, &out[idx]);
                        __builtin_nontemporal_store(mv[i], &out[TN + idx]);
                    }
            }
            // (b) stage phase ph+1
            if (ph + 1 < NPH) {
                const size_t tb = (size_t)(ph + 1) * PH_T;
                float v[NPART][10];
                int gi[10];
#pragma unroll
                for (int i = 0; i < 10; ++i) {
                    int g = wv + 7 * i;
                    gi[i] = g;
                    if (g < NGRP) {
                        size_t idx = (tb + g * 4 + tr) * N_OUT + n0 + pn;
#pragma unroll
                        for (int zz = 0; zz < NPART; ++zz)
                            v[zz][i] = bf2f(Pb[(size_t)zz * TN + idx]);
                    }
                }
#pragma unroll
                for (int i = 0; i < 10; ++i)
                    if (gi[i] < NGRP) {
                        float s = v[0][i];
#pragma unroll
                        for (int zz = 1; zz < NPART; ++zz) s += v[zz][i];
                        ringCur[(ph + 1) & 1][pn * TP + gi[i] * 4 + tr] = s;
                    }
            }
        } else if (lane < 16) {
            // consumer: PH_T serial steps out of ringCur[ph&1]
            const float* base = &ringCur[ph & 1][pn * TP];
            float* mbase = &ringMem[ph & 1][pn * TP];
#pragma unroll
            for (int sub = 0; sub < PH_T / 32; ++sub) {
                float2 buf[16];
#pragma unroll
                for (int q = 0; q < 16; ++q)
                    buf[q] = *(const float2*)&base[sub * 32 + q * 2];
#pragma unroll
                for (int q = 0; q < 16; ++q) {
                    float rst = mem > 1.0f ? 1.0f : 0.0f;
                    mem = fmaf(0.9f, mem, buf[q].x) - rst;
                    float m0 = mem;
                    rst = mem > 1.0f ? 1.0f : 0.0f;
                    mem = fmaf(0.9f, mem, buf[q].y) - rst;
                    float2 mo; mo.x = m0; mo.y = mem;
                    *(float2*)&mbase[sub * 32 + q * 2] = mo;
                }
            }
        }
        __syncthreads();
    }

    // ---- tail: write out phase NPH-1 ----
    if (wv < 7) {
        const float* mr = ringMem[(NPH - 1) & 1];
        const size_t tb = (size_t)(NPH - 1) * PH_T;
        float mv[10];
        int gi[10];
#pragma unroll
        for (int i = 0; i < 10; ++i) {
            int g = wv + 7 * i;
            gi[i] = g;
            if (g < NGRP) mv[i] = mr[pn * TP + g * 4 + tr];
        }
#pragma unroll
        for (int i = 0; i < 10; ++i)
            if (gi[i] < NGRP) {
                size_t idx = (tb + gi[i] * 4 + tr) * N_OUT + n0 + pn;
                __builtin_nontemporal_store(mv[i] > 1.0f ? 1.0f : 0.0f, &out[idx]);
                __builtin_nontemporal_store(mv[i], &out[TN + idx]);
            }
    }
}

extern "C" void kernel_launch(void* const* d_in, const int* in_sizes, int n_in,
                              void* d_out, int out_size, void* d_ws, size_t ws_size,
                              hipStream_t stream) {
    const float* x = (const float*)d_in[0];  // [1024][4096] fp32
    const float* W = (const float*)d_in[1];  // [4096][4096] fp32
    float* out = (float*)d_out;              // [2][1024][4096] fp32

    char* ws = (char*)d_ws;
    const size_t xbBytes = (size_t)T_STEPS * N_IN * 2;    // 8 MB
    const size_t WbBytes = (size_t)N_OUT * N_IN * 2;      // 33.6 MB
    const size_t PBytes  = TN * 2;                        // 8.4 MB per bf16 partial
    short* xb = (short*)ws;
    short* Wb = (short*)(ws + xbBytes);
    unsigned short* Pb = (unsigned short*)(ws + xbBytes + WbBytes);

    // Split-K: S=2 is the sweet spot (gemm occupancy vs scan re-read traffic)
    const int S = (ws_size >= xbBytes + WbBytes + 2 * PBytes) ? 2 : 1;

    {
        const int n4x = T_STEPS * N_IN / 4;
        const int n4w = N_OUT * N_IN / 4;
        const int nthr = n4x + n4w;
        cvt2_kernel<<<(nthr + 255) / 256, 256, 0, stream>>>(
            (const float4*)x, (ushort4*)xb, n4x,
            (const float4*)W, (ushort4*)Wb, n4w);
    }

    gemm_bt<<<256 * S, 256, 0, stream>>>(xb, Wb, Pb, N_IN / S);

    if (S == 2) scan_kernel<2><<<N_OUT / NB_N, 512, 0, stream>>>(Pb, out);
    else        scan_kernel<1><<<N_OUT / NB_N, 512, 0, stream>>>(Pb, out);
}

// Round 12
// 181.563 us; speedup vs baseline: 1.0284x; 1.0284x over previous
//
#include <hip/hip_runtime.h>
#include <hip/hip_bf16.h>
#include <stdint.h>

// ---------------------------------------------------------------------------
// Net_71373766525077: SNN leaky layer.
//   cur = x @ W^T   (1024x4096 @ 4096x4096 fp32; mem tol 7.92 -> bf16 MFMA)
//   scan t: reset=(mem>1); mem=0.9*mem+cur[t]-reset; spk=(mem>1)
//   out = concat(spk_rec[T][N], mem_rec[T][N]) fp32
//
// R11 -> R12: exact revert to R10 (best measured: 182.2us). R11's deeper
// scan phases (PH_T=256 + nontemporal) regressed 4.5us - doubled per-phase
// prefetch burst on the 512-thread producer block. Ledger: OV ~80 fixed +
// cvt 19 (BW floor) + gemm 56 (structure plateau) + scan ~27. This is the
// floor of the cvt->gemm->fused-scan decomposition from HIP source.
// ---------------------------------------------------------------------------

typedef __attribute__((ext_vector_type(8))) short bf16x8;
typedef __attribute__((ext_vector_type(4))) float floatx4;

#define T_STEPS 1024
#define N_IN    4096
#define N_OUT   4096

#define BM 128   // gemm M tile
#define BN 128   // gemm N tile
#define BKK 64   // K-chunk per LDS stage (bf16 elements)

#define PH_T 128                  // timesteps per scan phase
#define NPH  (T_STEPS / PH_T)     // 8 phases
#define NB_N 16                   // neurons per scan block
#define TP   130                  // LDS t-stride (floats)

#define TN ((size_t)T_STEPS * N_OUT)

__device__ __forceinline__ unsigned short f2bf_rne(float f) {
    unsigned int u = __builtin_bit_cast(unsigned int, f);
    unsigned int r = 0x7FFFu + ((u >> 16) & 1u);
    return (unsigned short)((u + r) >> 16);
}

__device__ __forceinline__ float bf2f(unsigned short b) {
    unsigned int u = ((unsigned int)b) << 16;
    return __builtin_bit_cast(float, u);
}

// One kernel converts both inputs (x then W), float4/ushort4 vectorized.
__global__ __launch_bounds__(256) void cvt2_kernel(const float4* __restrict__ inX,
                                                   ushort4* __restrict__ outX, int n4x,
                                                   const float4* __restrict__ inW,
                                                   ushort4* __restrict__ outW, int n4w) {
    int i = blockIdx.x * blockDim.x + threadIdx.x;
    const float4* in;
    ushort4* out;
    int k;
    if (i < n4x) { in = inX; out = outX; k = i; }
    else         { in = inW; out = outW; k = i - n4x; if (k >= n4w) return; }
    float4 v = in[k];
    ushort4 o;
    o.x = f2bf_rne(v.x);
    o.y = f2bf_rne(v.y);
    o.z = f2bf_rne(v.z);
    o.w = f2bf_rne(v.w);
    out[k] = o;
}

__device__ __forceinline__ void gload16(const void* g, void* l) {
    __builtin_amdgcn_global_load_lds((const __attribute__((address_space(1))) void*)g,
                                     (__attribute__((address_space(3))) void*)l,
                                     16, 0, 0);
}

// Pb[z][T][N] = A[M][kz] * B[N][kz]^T, bf16 in, bf16 partials out.
// 128x128 tile, grid = 256*S blocks (z = bid>>8, mt = (bid>>5)&7, nt = bid&31).
// 4 waves in 2x2, each 64x64 via 4x4 of 16x16x32 MFMA.
__global__ __launch_bounds__(256) void gemm_bt(const short* __restrict__ A,
                                               const short* __restrict__ B,
                                               unsigned short* __restrict__ Pb,
                                               int kLen) {
    __shared__ short sA[BM * BKK];  // 16 KB
    __shared__ short sB[BN * BKK];  // 16 KB

    const int tid  = threadIdx.x;
    const int lane = tid & 63;
    const int wv   = tid >> 6;
    const int wm   = (wv & 1) * 64;
    const int wn   = (wv >> 1) * 64;

    const int bid    = blockIdx.x;
    const int z      = bid >> 8;
    const int n_tile = bid & 31;
    const int m_tile = (bid >> 5) & 7;
    const long bm = (long)m_tile * BM;
    const long bn = (long)n_tile * BN;
    const int kBeg = z * kLen;
    const int kEnd = kBeg + kLen;
    unsigned short* __restrict__ Pz = Pb + (size_t)z * TN;

    floatx4 acc[4][4] = {};

    const int srow = tid >> 3;       // 0..31
    const int scol = (tid & 7) * 8;  // bf16 offset within 64-wide row
    const short* gA[4];
    const short* gB[4];
    short* lA[4];
    short* lB[4];
#pragma unroll
    for (int p = 0; p < 4; ++p) {
        gA[p] = A + (bm + p * 32 + srow) * (long)N_IN + scol;
        gB[p] = B + (bn + p * 32 + srow) * (long)N_IN + scol;
        lA[p] = sA + p * 2048 + tid * 8;
        lB[p] = sB + p * 2048 + tid * 8;
    }

    const int fm  = lane & 15;
    const int fko = (lane >> 4) * 8;

    for (int k0 = kBeg; k0 < kEnd; k0 += BKK) {
#pragma unroll
        for (int p = 0; p < 4; ++p) gload16(gA[p] + k0, lA[p]);
#pragma unroll
        for (int p = 0; p < 4; ++p) gload16(gB[p] + k0, lB[p]);
        __syncthreads();

#pragma unroll
        for (int ks = 0; ks < 2; ++ks) {
            bf16x8 af[4], bfr[4];
#pragma unroll
            for (int i = 0; i < 4; ++i)
                af[i] = *(const bf16x8*)(sA + (wm + i * 16 + fm) * 64 + ks * 32 + fko);
#pragma unroll
            for (int j = 0; j < 4; ++j)
                bfr[j] = *(const bf16x8*)(sB + (wn + j * 16 + fm) * 64 + ks * 32 + fko);
#pragma unroll
            for (int i = 0; i < 4; ++i)
#pragma unroll
                for (int j = 0; j < 4; ++j)
                    acc[i][j] = __builtin_amdgcn_mfma_f32_16x16x32_bf16(
                        af[i], bfr[j], acc[i][j], 0, 0, 0);
        }
        __syncthreads();
    }

    // C/D layout: col(n)=lane&15, row(m)=(lane>>4)*4+reg [m89/m91]
    const int cn = lane & 15;
    const int cm = (lane >> 4) * 4;
#pragma unroll
    for (int i = 0; i < 4; ++i)
#pragma unroll
        for (int j = 0; j < 4; ++j)
#pragma unroll
            for (int r = 0; r < 4; ++r)
                Pz[(bm + wm + i * 16 + cm + r) * (long)N_OUT + bn + wn + j * 16 + cn] =
                    f2bf_rne(acc[i][j][r]);
}

// Fused scan: 256 blocks x 512 threads; block owns NB_N=16 neurons for ALL t.
// Waves 0-6 (producers): write out phase ph-1 spk/mem from ringMem, stage
// phase ph+1 of Pb (bf16, summing NPART partials) into ringCur. Wave 7
// (consumer, lanes 0..15): serial recurrence ringCur -> ringMem.
// Producer lane map: pn=lane&15 (n), tr=lane>>4 (t-row in group of 4);
// row-groups g = wv + 7*i, i<5, guard g<32.
template <int NPART>
__global__ __launch_bounds__(512) void scan_kernel(const unsigned short* __restrict__ Pb,
                                                   float* __restrict__ out) {
    __shared__ float ringCur[2][NB_N * TP];   // 16.6 KB
    __shared__ float ringMem[2][NB_N * TP];   // 16.6 KB

    const int tid  = threadIdx.x;
    const int wv   = tid >> 6;     // 0..7
    const int lane = tid & 63;
    const int n0   = blockIdx.x * NB_N;

    const int pn = lane & 15;   // neuron offset within block
    const int tr = lane >> 4;   // t-row 0..3 within a group of 4

    float mem = 0.0f;           // consumer state (wave 7, lanes 0..15)

    // ---- prefill: phase 0 -> ringCur[0] ----
    if (wv < 7) {
        float v[NPART][5];
        int gi[5];
#pragma unroll
        for (int i = 0; i < 5; ++i) {
            int g = wv + 7 * i;
            gi[i] = g;
            if (g < 32) {
                size_t idx = (size_t)(g * 4 + tr) * N_OUT + n0 + pn;
#pragma unroll
                for (int zz = 0; zz < NPART; ++zz)
                    v[zz][i] = bf2f(Pb[(size_t)zz * TN + idx]);
            }
        }
#pragma unroll
        for (int i = 0; i < 5; ++i)
            if (gi[i] < 32) {
                float s = v[0][i];
#pragma unroll
                for (int zz = 1; zz < NPART; ++zz) s += v[zz][i];
                ringCur[0][pn * TP + gi[i] * 4 + tr] = s;
            }
    }
    __syncthreads();

    for (int ph = 0; ph < NPH; ++ph) {
        if (wv < 7) {
            // (a) write out phase ph-1 results
            if (ph >= 1) {
                const float* mr = ringMem[(ph - 1) & 1];
                const size_t tb = (size_t)(ph - 1) * PH_T;
                float mv[5];
                int gi[5];
#pragma unroll
                for (int i = 0; i < 5; ++i) {
                    int g = wv + 7 * i;
                    gi[i] = g;
                    if (g < 32) mv[i] = mr[pn * TP + g * 4 + tr];
                }
#pragma unroll
                for (int i = 0; i < 5; ++i)
                    if (gi[i] < 32) {
                        size_t idx = (tb + gi[i] * 4 + tr) * N_OUT + n0 + pn;
                        out[idx]      = mv[i] > 1.0f ? 1.0f : 0.0f;
                        out[TN + idx] = mv[i];
                    }
            }
            // (b) stage phase ph+1
            if (ph + 1 < NPH) {
                const size_t tb = (size_t)(ph + 1) * PH_T;
                float v[NPART][5];
                int gi[5];
#pragma unroll
                for (int i = 0; i < 5; ++i) {
                    int g = wv + 7 * i;
                    gi[i] = g;
                    if (g < 32) {
                        size_t idx = (tb + g * 4 + tr) * N_OUT + n0 + pn;
#pragma unroll
                        for (int zz = 0; zz < NPART; ++zz)
                            v[zz][i] = bf2f(Pb[(size_t)zz * TN + idx]);
                    }
                }
#pragma unroll
                for (int i = 0; i < 5; ++i)
                    if (gi[i] < 32) {
                        float s = v[0][i];
#pragma unroll
                        for (int zz = 1; zz < NPART; ++zz) s += v[zz][i];
                        ringCur[(ph + 1) & 1][pn * TP + gi[i] * 4 + tr] = s;
                    }
            }
        } else if (lane < 16) {
            // consumer: 128 serial steps out of ringCur[ph&1]
            const float* base = &ringCur[ph & 1][pn * TP];
            float* mbase = &ringMem[ph & 1][pn * TP];
#pragma unroll
            for (int sub = 0; sub < 4; ++sub) {
                float2 buf[16];
#pragma unroll
                for (int q = 0; q < 16; ++q)
                    buf[q] = *(const float2*)&base[sub * 32 + q * 2];
#pragma unroll
                for (int q = 0; q < 16; ++q) {
                    float rst = mem > 1.0f ? 1.0f : 0.0f;
                    mem = fmaf(0.9f, mem, buf[q].x) - rst;
                    float m0 = mem;
                    rst = mem > 1.0f ? 1.0f : 0.0f;
                    mem = fmaf(0.9f, mem, buf[q].y) - rst;
                    float2 mo; mo.x = m0; mo.y = mem;
                    *(float2*)&mbase[sub * 32 + q * 2] = mo;
                }
            }
        }
        __syncthreads();
    }

    // ---- tail: write out phase NPH-1 ----
    if (wv < 7) {
        const float* mr = ringMem[(NPH - 1) & 1];
        const size_t tb = (size_t)(NPH - 1) * PH_T;
        float mv[5];
        int gi[5];
#pragma unroll
        for (int i = 0; i < 5; ++i) {
            int g = wv + 7 * i;
            gi[i] = g;
            if (g < 32) mv[i] = mr[pn * TP + g * 4 + tr];
        }
#pragma unroll
        for (int i = 0; i < 5; ++i)
            if (gi[i] < 32) {
                size_t idx = (tb + gi[i] * 4 + tr) * N_OUT + n0 + pn;
                out[idx]      = mv[i] > 1.0f ? 1.0f : 0.0f;
                out[TN + idx] = mv[i];
            }
    }
}

extern "C" void kernel_launch(void* const* d_in, const int* in_sizes, int n_in,
                              void* d_out, int out_size, void* d_ws, size_t ws_size,
                              hipStream_t stream) {
    const float* x = (const float*)d_in[0];  // [1024][4096] fp32
    const float* W = (const float*)d_in[1];  // [4096][4096] fp32
    float* out = (float*)d_out;              // [2][1024][4096] fp32

    char* ws = (char*)d_ws;
    const size_t xbBytes = (size_t)T_STEPS * N_IN * 2;    // 8 MB
    const size_t WbBytes = (size_t)N_OUT * N_IN * 2;      // 33.6 MB
    const size_t PBytes  = TN * 2;                        // 8.4 MB per bf16 partial
    short* xb = (short*)ws;
    short* Wb = (short*)(ws + xbBytes);
    unsigned short* Pb = (unsigned short*)(ws + xbBytes + WbBytes);

    // Split-K: S=2 is the sweet spot (gemm occupancy vs scan re-read traffic)
    const int S = (ws_size >= xbBytes + WbBytes + 2 * PBytes) ? 2 : 1;

    {
        const int n4x = T_STEPS * N_IN / 4;
        const int n4w = N_OUT * N_IN / 4;
        const int nthr = n4x + n4w;
        cvt2_kernel<<<(nthr + 255) / 256, 256, 0, stream>>>(
            (const float4*)x, (ushort4*)xb, n4x,
            (const float4*)W, (ushort4*)Wb, n4w);
    }

    gemm_bt<<<256 * S, 256, 0, stream>>>(xb, Wb, Pb, N_IN / S);

    if (S == 2) scan_kernel<2><<<N_OUT / NB_N, 512, 0, stream>>>(Pb, out);
    else        scan_kernel<1><<<N_OUT / NB_N, 512, 0, stream>>>(Pb, out);
}